// Round 7
// baseline (508.747 us; speedup 1.0000x reference)
//
#include <hip/hip_runtime.h>
#include <hip/hip_bf16.h>
#include <stdint.h>

#define Bdim 4
#define Hdim 8
#define Ndim 2048
#define Cdim 512
#define Ddim 64
#define SCALE_F 0.125f
#define SOFTMAX_SHIFT 30.0f
#define KSPLIT 2

typedef __bf16 bf16_t;
typedef __bf16 bf16x8 __attribute__((ext_vector_type(8)));
typedef float f32x4 __attribute__((ext_vector_type(4)));

// xor-swizzle lane shuffle within 32-lane groups (BitMode: and=0x1F, xor=m)
#define SWZ_XOR_F(v, m) \
  __int_as_float(__builtin_amdgcn_ds_swizzle(__float_as_int(v), (0x1F | ((m) << 10))))

// ---------------------------------------------------------------------------
// Gumbel noise: JAX threefry2x32, key (0,42), partitionable path:
// counter words (hi=0, lo=flat), bits32 = out0 ^ out1.
// u = bitcast(bits>>9 | 0x3f800000) - 1 + tiny ; g = -log(-log(u))
// ---------------------------------------------------------------------------
__device__ __forceinline__ float gumbel_noise(uint32_t flat) {
  const uint32_t k0 = 0u, k1 = 42u, k2 = 0x1BD11BDAu ^ 0u ^ 42u;
  uint32_t x0 = 0u;          // counter hi word (flat < 2^32)
  uint32_t x1 = flat;        // counter lo word
  x0 += k0; x1 += k1;
#define TF_R(r) { x0 += x1; x1 = __builtin_rotateleft32(x1, r); x1 ^= x0; }
#define TF_R4A TF_R(13) TF_R(15) TF_R(26) TF_R(6)
#define TF_R4B TF_R(17) TF_R(29) TF_R(16) TF_R(24)
  TF_R4A  x0 += k1; x1 += k2 + 1u;
  TF_R4B  x0 += k2; x1 += k0 + 2u;
  TF_R4A  x0 += k0; x1 += k1 + 3u;
  TF_R4B  x0 += k1; x1 += k2 + 4u;
  TF_R4A  x0 += k2; x1 += k0 + 5u;
#undef TF_R4B
#undef TF_R4A
#undef TF_R
  uint32_t bits = x0 ^ x1;   // partitionable 32-bit fold
  float f = __uint_as_float((bits >> 9) | 0x3F800000u) - 1.0f;
  float u = f + 1.17549435e-38f;           // matches jax uniform(minval=tiny)
  return -__logf(-__logf(u));
}

// ---------------------------------------------------------------------------
// fp32 -> bf16 convert (8 elems/thread)
// ---------------------------------------------------------------------------
__global__ void cvt_f32_bf16(const float* __restrict__ in,
                             bf16_t* __restrict__ out, int n8) {
  int i = blockIdx.x * blockDim.x + threadIdx.x;
  if (i < n8) {
    const float4* p = (const float4*)in + (size_t)i * 2;
    float4 a = p[0], b = p[1];
    union { bf16_t h[8]; uint4 u; } pk;
    pk.h[0] = (bf16_t)a.x; pk.h[1] = (bf16_t)a.y;
    pk.h[2] = (bf16_t)a.z; pk.h[3] = (bf16_t)a.w;
    pk.h[4] = (bf16_t)b.x; pk.h[5] = (bf16_t)b.y;
    pk.h[6] = (bf16_t)b.z; pk.h[7] = (bf16_t)b.w;
    *((uint4*)out + i) = pk.u;
  }
}

// ---------------------------------------------------------------------------
// NT GEMM core: C[m][n] = sum_k A[m0+m][k] * W[n0+n][k], K = 512.
// Block 256 thr = 4 waves (2x2), each wave 64x64. Tiles 128x128, BK = 64.
// mfma_f32_16x16x32_bf16: A/B frag [row=lane&15][k=quad*8+j], C/D row=quad*4+r.
// ---------------------------------------------------------------------------
__device__ __forceinline__ void gemm_core(const bf16_t* __restrict__ A,
                                          const bf16_t* __restrict__ W,
                                          int m0, int n0,
                                          bf16_t* As, bf16_t* Ws,
                                          f32x4 (&acc)[4][4]) {
  const int t = threadIdx.x;
  const int wave = t >> 6, lane = t & 63;
  const int ln = lane & 15, qd = lane >> 4;
  const int wm = wave >> 1, wn = wave & 1;

#pragma unroll
  for (int i = 0; i < 4; i++)
#pragma unroll
    for (int j = 0; j < 4; j++) acc[i][j] = (f32x4){0.f, 0.f, 0.f, 0.f};

  for (int kt = 0; kt < Cdim / 64; ++kt) {
#pragma unroll
    for (int it = 0; it < 4; ++it) {
      int vec = it * 256 + t;
      int row = vec >> 3, c8 = (vec & 7) * 8;
      *(bf16x8*)&As[row * 72 + c8] =
          *(const bf16x8*)&A[(size_t)(m0 + row) * Cdim + kt * 64 + c8];
      *(bf16x8*)&Ws[row * 72 + c8] =
          *(const bf16x8*)&W[(size_t)(n0 + row) * Cdim + kt * 64 + c8];
    }
    __syncthreads();
#pragma unroll
    for (int ks = 0; ks < 2; ++ks) {
      bf16x8 af[4], bfr[4];
#pragma unroll
      for (int i = 0; i < 4; i++)
        af[i] = *(const bf16x8*)&As[(wm * 64 + i * 16 + ln) * 72 + ks * 32 + qd * 8];
#pragma unroll
      for (int j = 0; j < 4; j++)
        bfr[j] = *(const bf16x8*)&Ws[(wn * 64 + j * 16 + ln) * 72 + ks * 32 + qd * 8];
#pragma unroll
      for (int i = 0; i < 4; i++)
#pragma unroll
        for (int j = 0; j < 4; j++)
          acc[i][j] = __builtin_amdgcn_mfma_f32_16x16x32_bf16(af[i], bfr[j],
                                                              acc[i][j], 0, 0, 0);
    }
    __syncthreads();
  }
}

// QKV projections fused over blockIdx.z; epilogue scatters to [B,H,L,D] bf16.
// Q (sel==0) is pre-scaled by SCALE_F so attn logits need no per-element mul.
__global__ __launch_bounds__(256, 2)
void qkv_gemm_kernel(const bf16_t* __restrict__ xb, const bf16_t* __restrict__ yb,
                     const bf16_t* __restrict__ zb, const bf16_t* __restrict__ wqb,
                     const bf16_t* __restrict__ wkb, const bf16_t* __restrict__ wvb,
                     const float* __restrict__ bq, const float* __restrict__ bk,
                     const float* __restrict__ bv, bf16_t* __restrict__ qo,
                     bf16_t* __restrict__ ko, bf16_t* __restrict__ vo) {
  __shared__ bf16_t As[128 * 72];
  __shared__ bf16_t Ws[128 * 72];
  const int sel = blockIdx.z;
  const bf16_t* A = sel == 0 ? xb : (sel == 1 ? yb : zb);
  const bf16_t* W = sel == 0 ? wqb : (sel == 1 ? wkb : wvb);
  const float* bias = sel == 0 ? bq : (sel == 1 ? bk : bv);
  bf16_t* O = sel == 0 ? qo : (sel == 1 ? ko : vo);
  const float mul = sel == 0 ? SCALE_F : 1.0f;
  const int m0 = blockIdx.y * 128, n0 = blockIdx.x * 128;

  f32x4 acc[4][4];
  gemm_core(A, W, m0, n0, As, Ws, acc);

  const int t = threadIdx.x;
  const int wave = t >> 6, lane = t & 63;
  const int ln = lane & 15, qd = lane >> 4;
  const int wm = wave >> 1, wn = wave & 1;
#pragma unroll
  for (int i = 0; i < 4; i++)
#pragma unroll
    for (int j = 0; j < 4; j++)
#pragma unroll
      for (int r = 0; r < 4; r++) {
        int grow = m0 + wm * 64 + i * 16 + qd * 4 + r;
        int gcol = n0 + wn * 64 + j * 16 + ln;
        float val = (acc[i][j][r] + bias[gcol]) * mul;
        int b = grow >> 11, n = grow & 2047;
        int h = gcol >> 6, d = gcol & 63;
        O[(((size_t)b * Hdim + h) * Ndim + n) * Ddim + d] = (bf16_t)val;
      }
}

// Output projection: attn_out[8192,512] bf16 @ Wo^T + bo -> fp32 d_out
__global__ __launch_bounds__(256, 2)
void out_gemm_kernel(const bf16_t* __restrict__ ab, const bf16_t* __restrict__ wob,
                     const float* __restrict__ bo, float* __restrict__ out) {
  __shared__ bf16_t As[128 * 72];
  __shared__ bf16_t Ws[128 * 72];
  const int m0 = blockIdx.y * 128, n0 = blockIdx.x * 128;
  f32x4 acc[4][4];
  gemm_core(ab, wob, m0, n0, As, Ws, acc);

  const int t = threadIdx.x;
  const int wave = t >> 6, lane = t & 63;
  const int ln = lane & 15, qd = lane >> 4;
  const int wm = wave >> 1, wn = wave & 1;
#pragma unroll
  for (int i = 0; i < 4; i++)
#pragma unroll
    for (int j = 0; j < 4; j++)
#pragma unroll
      for (int r = 0; r < 4; r++) {
        int grow = m0 + wm * 64 + i * 16 + qd * 4 + r;
        int gcol = n0 + wn * 64 + j * 16 + ln;
        out[(size_t)grow * Cdim + gcol] = acc[i][j][r] + bo[gcol];
      }
}

// ---------------------------------------------------------------------------
// Flash-style Gumbel attention, fixed-shift softmax, key-split by KSPLIT.
// K B-fragments are loaded straight from global (register-shaped, no LDS, no
// transpose): lane ln reads K[kt*64+j*16+ln][qd*8 (+32)] as two 16B loads.
// K is LLC-resident, so the 4x intra-block duplication is L2 traffic only.
// LDS = Vt + Ps = 18.4 KB -> 8 blocks/CU; grid = 8 blocks/CU -> a single
// full-occupancy generation (32 waves/CU). launch_bounds(256,8) caps VGPR 64.
// Partials additive across key halves: o = sum(o_z) / sum(l_z).
// ---------------------------------------------------------------------------
__global__ __launch_bounds__(256, 8)
void attn_kernel(const bf16_t* __restrict__ qb, const bf16_t* __restrict__ kb,
                 const bf16_t* __restrict__ vb, float* __restrict__ part_o,
                 float* __restrict__ part_l) {
  __shared__ bf16_t Vt[64 * 72];   // swizzled transpose: (d,key) at d*72+((key>>3)^(d>>3))*8+(key&7)
  __shared__ bf16_t Ps[64 * 72];

  const int t = threadIdx.x;
  const int wave = t >> 6, lane = t & 63;
  const int ln = lane & 15, qd = lane >> 4;
  const int qtile = blockIdx.x;    // 0..31
  const int bh = blockIdx.y;       // 0..31
  const int z = blockIdx.z;        // 0..KSPLIT-1
  const int qbase = qtile * 64;
  const int kt_lo = z * (Ndim / 64 / KSPLIT);
  const int kt_hi = kt_lo + (Ndim / 64 / KSPLIT);

  const bf16_t* Qg = qb + (size_t)bh * Ndim * Ddim;
  const bf16_t* Kg = kb + (size_t)bh * Ndim * Ddim;
  const bf16_t* Vg = vb + (size_t)bh * Ndim * Ddim;

  // Q A-fragments in registers: rows wave*16+ln, cols ks*32+qd*8..+8
  const bf16_t* Qrow = Qg + (size_t)(qbase + wave * 16 + ln) * Ddim;
  bf16x8 qf0 = *(const bf16x8*)&Qrow[qd * 8];
  bf16x8 qf1 = *(const bf16x8*)&Qrow[32 + qd * 8];

  float l_r[4] = {0.f, 0.f, 0.f, 0.f};
  f32x4 o_acc[4];
#pragma unroll
  for (int j = 0; j < 4; j++) o_acc[j] = (f32x4){0.f, 0.f, 0.f, 0.f};

  const uint32_t flat_bh = (uint32_t)bh << 22;

  for (int kt = kt_lo; kt < kt_hi; ++kt) {
    // stage V (swizzled transpose) into LDS
#pragma unroll
    for (int it = 0; it < 2; ++it) {
      int vec = it * 256 + t;
      int row = vec >> 3, c8 = (vec & 7) * 8;
      bf16x8 vv = *(const bf16x8*)&Vg[(size_t)(kt * 64 + row) * Ddim + c8];
      int swz_base = ((row >> 3) ^ (c8 >> 3)) * 8 + (row & 7);
#pragma unroll
      for (int jj = 0; jj < 8; jj++)
        Vt[(c8 + jj) * 72 + swz_base] = vv[jj];
    }
    __syncthreads();

    // S tile: wave rows 16w..16w+15, cols 64; K B-frags from global
    const bf16_t* Kt = Kg + (size_t)(kt * 64 + ln) * Ddim + qd * 8;
    f32x4 s[4];
#pragma unroll
    for (int j = 0; j < 4; j++) s[j] = (f32x4){0.f, 0.f, 0.f, 0.f};
#pragma unroll
    for (int j = 0; j < 4; j++) {
      bf16x8 bk0 = *(const bf16x8*)&Kt[j * 16 * Ddim];
      bf16x8 bk1 = *(const bf16x8*)&Kt[j * 16 * Ddim + 32];
      s[j] = __builtin_amdgcn_mfma_f32_16x16x32_bf16(qf0, bk0, s[j], 0, 0, 0);
      s[j] = __builtin_amdgcn_mfma_f32_16x16x32_bf16(qf1, bk1, s[j], 0, 0, 0);
    }

    // gumbel + fixed-shift exp; accumulate per-lane l, stage P to LDS
#pragma unroll
    for (int r = 0; r < 4; r++) {
      int qrow = qbase + wave * 16 + qd * 4 + r;
      uint32_t fbase = flat_bh + ((uint32_t)qrow << 11) + (uint32_t)(kt * 64 + ln);
#pragma unroll
      for (int j = 0; j < 4; j++) {
        float sv = s[j][r] + gumbel_noise(fbase + j * 16) - SOFTMAX_SHIFT;
        float pv = __expf(sv);
        l_r[r] += pv;
        Ps[(wave * 16 + qd * 4 + r) * 72 + j * 16 + ln] = (bf16_t)pv;
      }
    }
    // Ps produced and consumed by the same wave -> no barrier needed

    // O += P V  (A = P rows 16w.., B[n=d][k=key] from swizzled Vt)
#pragma unroll
    for (int ks = 0; ks < 2; ++ks) {
      bf16x8 af = *(const bf16x8*)&Ps[(wave * 16 + ln) * 72 + ks * 32 + qd * 8];
#pragma unroll
      for (int j = 0; j < 4; j++) {
        int d = j * 16 + ln;
        bf16x8 bv8 = *(const bf16x8*)&Vt[d * 72 + (((ks * 4 + qd) ^ (d >> 3)) << 3)];
        o_acc[j] = __builtin_amdgcn_mfma_f32_16x16x32_bf16(af, bv8, o_acc[j], 0, 0, 0);
      }
    }
    __syncthreads();  // protect Vt before next staging
  }

  // epilogue: write f32 partials (o in C-layout rows, l per row once)
  const int pidx = ((bh << 5) | qtile) * KSPLIT + z;
  float* po = part_o + (size_t)pidx * 64 * 64;
  float* pl = part_l + (size_t)pidx * 64;

  // reduce l across the 16 ln-lanes of each row group; lane ln==0 stores
#pragma unroll
  for (int r = 0; r < 4; r++) {
    float lsum = l_r[r];
    lsum += SWZ_XOR_F(lsum, 1);
    lsum += SWZ_XOR_F(lsum, 2);
    lsum += SWZ_XOR_F(lsum, 4);
    lsum += SWZ_XOR_F(lsum, 8);
    if (ln == 0) pl[wave * 16 + qd * 4 + r] = lsum;
  }
#pragma unroll
  for (int j = 0; j < 4; j++)
#pragma unroll
    for (int r = 0; r < 4; r++) {
      int row = wave * 16 + qd * 4 + r;
      int col = j * 16 + ln;
      po[row * 64 + col] = o_acc[j][r];
    }
}

// ---------------------------------------------------------------------------
// Combine: ab[b][qrow][h*64+d] = sum_z(o_z) / sum_z(l_z), bf16.
// One block per (bh,qtile); thread t: row = t>>2, 16 cols starting (t&3)*16.
// ---------------------------------------------------------------------------
__global__ __launch_bounds__(256, 8)
void attn_combine(const float* __restrict__ part_o,
                  const float* __restrict__ part_l, bf16_t* __restrict__ ab) {
  const int blk = blockIdx.x;      // bh*32 + qtile
  const int bh = blk >> 5, qtile = blk & 31;
  const float* o0 = part_o + (size_t)(blk * KSPLIT + 0) * 64 * 64;
  const float* o1 = part_o + (size_t)(blk * KSPLIT + 1) * 64 * 64;
  const float* l0 = part_l + (size_t)(blk * KSPLIT + 0) * 64;
  const float* l1 = part_l + (size_t)(blk * KSPLIT + 1) * 64;

  const int t = threadIdx.x;
  const int row = t >> 2, c0 = (t & 3) * 16;
  const float linv = 1.0f / (l0[row] + l1[row]);
  const int b = bh >> 3, h = bh & 7;
  bf16_t* dst = ab + ((size_t)b * Ndim + qtile * 64 + row) * Cdim + h * 64 + c0;

#pragma unroll
  for (int i = 0; i < 4; i++) {
    float4 a = *(const float4*)&o0[row * 64 + c0 + i * 4];
    float4 c = *(const float4*)&o1[row * 64 + c0 + i * 4];
    union { bf16_t h4[4]; uint2 u; } pk;
    pk.h4[0] = (bf16_t)((a.x + c.x) * linv);
    pk.h4[1] = (bf16_t)((a.y + c.y) * linv);
    pk.h4[2] = (bf16_t)((a.z + c.z) * linv);
    pk.h4[3] = (bf16_t)((a.w + c.w) * linv);
    *(uint2*)&dst[i * 4] = pk.u;
  }
}

// ---------------------------------------------------------------------------
extern "C" void kernel_launch(void* const* d_in, const int* in_sizes, int n_in,
                              void* d_out, int out_size, void* d_ws, size_t ws_size,
                              hipStream_t stream) {
  const float* x  = (const float*)d_in[0];
  const float* y  = (const float*)d_in[1];
  const float* z  = (const float*)d_in[2];
  const float* Wq = (const float*)d_in[3];
  const float* bq = (const float*)d_in[4];
  const float* Wk = (const float*)d_in[5];
  const float* bk = (const float*)d_in[6];
  const float* Wv = (const float*)d_in[7];
  const float* bv = (const float*)d_in[8];
  const float* Wo = (const float*)d_in[9];
  const float* bo = (const float*)d_in[10];
  float* out = (float*)d_out;

  bf16_t* base = (bf16_t*)d_ws;
  const size_t NBIG = (size_t)Bdim * Ndim * Cdim;  // 4194304
  const size_t NW   = (size_t)Cdim * Cdim;         // 262144
  bf16_t* xb  = base;
  bf16_t* yb  = xb + NBIG;
  bf16_t* zb  = yb + NBIG;
  bf16_t* wqb = zb + NBIG;
  bf16_t* wkb = wqb + NW;
  bf16_t* wvb = wkb + NW;
  bf16_t* wob = wvb + NW;
  bf16_t* qb  = wob + NW;
  bf16_t* kb  = qb + NBIG;
  bf16_t* vb  = kb + NBIG;
  bf16_t* ab  = vb + NBIG;
  float* part_o = (float*)(ab + NBIG);            // 1024*KSPLIT*4096 f32
  float* part_l = part_o + (size_t)1024 * KSPLIT * 64 * 64;  // 1024*KSPLIT*64 f32

  int n8b = (int)(NBIG / 8), n8w = (int)(NW / 8);
  cvt_f32_bf16<<<n8b / 256, 256, 0, stream>>>(x, xb, n8b);
  cvt_f32_bf16<<<n8b / 256, 256, 0, stream>>>(y, yb, n8b);
  cvt_f32_bf16<<<n8b / 256, 256, 0, stream>>>(z, zb, n8b);
  cvt_f32_bf16<<<n8w / 256, 256, 0, stream>>>(Wq, wqb, n8w);
  cvt_f32_bf16<<<n8w / 256, 256, 0, stream>>>(Wk, wkb, n8w);
  cvt_f32_bf16<<<n8w / 256, 256, 0, stream>>>(Wv, wvb, n8w);
  cvt_f32_bf16<<<n8w / 256, 256, 0, stream>>>(Wo, wob, n8w);

  qkv_gemm_kernel<<<dim3(Cdim / 128, (Bdim * Ndim) / 128, 3), 256, 0, stream>>>(
      xb, yb, zb, wqb, wkb, wvb, bq, bk, bv, qb, kb, vb);

  attn_kernel<<<dim3(Ndim / 64, Bdim * Hdim, KSPLIT), 256, 0, stream>>>(
      qb, kb, vb, part_o, part_l);

  attn_combine<<<dim3(1024), 256, 0, stream>>>(part_o, part_l, ab);

  out_gemm_kernel<<<dim3(Cdim / 128, (Bdim * Ndim) / 128), 256, 0, stream>>>(
      ab, wob, bo, out);
}

// Round 8
// 440.490 us; speedup vs baseline: 1.1550x; 1.1550x over previous
//
#include <hip/hip_runtime.h>
#include <hip/hip_bf16.h>
#include <stdint.h>

#define Bdim 4
#define Hdim 8
#define Ndim 2048
#define Cdim 512
#define Ddim 64
#define SCALE_F 0.125f
#define KSPLIT 4
#define LOG2E 1.44269504f

typedef __bf16 bf16_t;
typedef __bf16 bf16x8 __attribute__((ext_vector_type(8)));
typedef float f32x4 __attribute__((ext_vector_type(4)));

// xor-swizzle lane shuffle within 32-lane groups (BitMode: and=0x1F, xor=m)
#define SWZ_XOR_F(v, m) \
  __int_as_float(__builtin_amdgcn_ds_swizzle(__float_as_int(v), (0x1F | ((m) << 10))))

// ---------------------------------------------------------------------------
// Gumbel factor: JAX threefry2x32, key (0,42), partitionable path:
// counter words (hi=0, lo=flat), bits32 = out0 ^ out1.
// u = bitcast(bits>>9 | 0x3f800000) - 1 + tiny.
// Softmax identity: exp(s + g) = exp(s)/(-ln u) = ln2 * exp2(s*log2e)*(-1/log2 u)
// and the global ln2 cancels in p/l. Return pf = -rcp(log2(u)).
// ---------------------------------------------------------------------------
__device__ __forceinline__ float gumbel_pfac(uint32_t flat) {
  const uint32_t k0 = 0u, k1 = 42u, k2 = 0x1BD11BDAu ^ 0u ^ 42u;
  uint32_t x0 = 0u;          // counter hi word (flat < 2^32)
  uint32_t x1 = flat;        // counter lo word
  x0 += k0; x1 += k1;
#define TF_R(r) { x0 += x1; x1 = __builtin_rotateleft32(x1, r); x1 ^= x0; }
#define TF_R4A TF_R(13) TF_R(15) TF_R(26) TF_R(6)
#define TF_R4B TF_R(17) TF_R(29) TF_R(16) TF_R(24)
  TF_R4A  x0 += k1; x1 += k2 + 1u;
  TF_R4B  x0 += k2; x1 += k0 + 2u;
  TF_R4A  x0 += k0; x1 += k1 + 3u;
  TF_R4B  x0 += k1; x1 += k2 + 4u;
  TF_R4A  x0 += k2; x1 += k0 + 5u;
#undef TF_R4B
#undef TF_R4A
#undef TF_R
  uint32_t bits = x0 ^ x1;   // partitionable 32-bit fold
  float f = __uint_as_float((bits >> 9) | 0x3F800000u) - 1.0f;
  float u = f + 1.17549435e-38f;           // matches jax uniform(minval=tiny)
  return -__builtin_amdgcn_rcpf(__builtin_amdgcn_logf(u));  // -1/log2(u)
}

// ---------------------------------------------------------------------------
// fp32 -> bf16 convert (8 elems/thread)
// ---------------------------------------------------------------------------
__global__ void cvt_f32_bf16(const float* __restrict__ in,
                             bf16_t* __restrict__ out, int n8) {
  int i = blockIdx.x * blockDim.x + threadIdx.x;
  if (i < n8) {
    const float4* p = (const float4*)in + (size_t)i * 2;
    float4 a = p[0], b = p[1];
    union { bf16_t h[8]; uint4 u; } pk;
    pk.h[0] = (bf16_t)a.x; pk.h[1] = (bf16_t)a.y;
    pk.h[2] = (bf16_t)a.z; pk.h[3] = (bf16_t)a.w;
    pk.h[4] = (bf16_t)b.x; pk.h[5] = (bf16_t)b.y;
    pk.h[6] = (bf16_t)b.z; pk.h[7] = (bf16_t)b.w;
    *((uint4*)out + i) = pk.u;
  }
}

// ---------------------------------------------------------------------------
// NT GEMM core: C[m][n] = sum_k A[m0+m][k] * W[n0+n][k], K = 512.
// Block 256 thr = 4 waves (2x2), each wave 64x64. Tiles 128x128, BK = 64.
// mfma_f32_16x16x32_bf16: A/B frag [row=lane&15][k=quad*8+j], C/D row=quad*4+r.
// ---------------------------------------------------------------------------
__device__ __forceinline__ void gemm_core(const bf16_t* __restrict__ A,
                                          const bf16_t* __restrict__ W,
                                          int m0, int n0,
                                          bf16_t* As, bf16_t* Ws,
                                          f32x4 (&acc)[4][4]) {
  const int t = threadIdx.x;
  const int wave = t >> 6, lane = t & 63;
  const int ln = lane & 15, qd = lane >> 4;
  const int wm = wave >> 1, wn = wave & 1;

#pragma unroll
  for (int i = 0; i < 4; i++)
#pragma unroll
    for (int j = 0; j < 4; j++) acc[i][j] = (f32x4){0.f, 0.f, 0.f, 0.f};

  for (int kt = 0; kt < Cdim / 64; ++kt) {
#pragma unroll
    for (int it = 0; it < 4; ++it) {
      int vec = it * 256 + t;
      int row = vec >> 3, c8 = (vec & 7) * 8;
      *(bf16x8*)&As[row * 72 + c8] =
          *(const bf16x8*)&A[(size_t)(m0 + row) * Cdim + kt * 64 + c8];
      *(bf16x8*)&Ws[row * 72 + c8] =
          *(const bf16x8*)&W[(size_t)(n0 + row) * Cdim + kt * 64 + c8];
    }
    __syncthreads();
#pragma unroll
    for (int ks = 0; ks < 2; ++ks) {
      bf16x8 af[4], bfr[4];
#pragma unroll
      for (int i = 0; i < 4; i++)
        af[i] = *(const bf16x8*)&As[(wm * 64 + i * 16 + ln) * 72 + ks * 32 + qd * 8];
#pragma unroll
      for (int j = 0; j < 4; j++)
        bfr[j] = *(const bf16x8*)&Ws[(wn * 64 + j * 16 + ln) * 72 + ks * 32 + qd * 8];
#pragma unroll
      for (int i = 0; i < 4; i++)
#pragma unroll
        for (int j = 0; j < 4; j++)
          acc[i][j] = __builtin_amdgcn_mfma_f32_16x16x32_bf16(af[i], bfr[j],
                                                              acc[i][j], 0, 0, 0);
    }
    __syncthreads();
  }
}

// QKV projections fused over blockIdx.z; epilogue scatters to [B,H,L,D] bf16.
// Q (sel==0) is pre-scaled by SCALE_F so attn logits need no per-element mul.
__global__ __launch_bounds__(256, 2)
void qkv_gemm_kernel(const bf16_t* __restrict__ xb, const bf16_t* __restrict__ yb,
                     const bf16_t* __restrict__ zb, const bf16_t* __restrict__ wqb,
                     const bf16_t* __restrict__ wkb, const bf16_t* __restrict__ wvb,
                     const float* __restrict__ bq, const float* __restrict__ bk,
                     const float* __restrict__ bv, bf16_t* __restrict__ qo,
                     bf16_t* __restrict__ ko, bf16_t* __restrict__ vo) {
  __shared__ bf16_t As[128 * 72];
  __shared__ bf16_t Ws[128 * 72];
  const int sel = blockIdx.z;
  const bf16_t* A = sel == 0 ? xb : (sel == 1 ? yb : zb);
  const bf16_t* W = sel == 0 ? wqb : (sel == 1 ? wkb : wvb);
  const float* bias = sel == 0 ? bq : (sel == 1 ? bk : bv);
  bf16_t* O = sel == 0 ? qo : (sel == 1 ? ko : vo);
  const float mul = sel == 0 ? SCALE_F : 1.0f;
  const int m0 = blockIdx.y * 128, n0 = blockIdx.x * 128;

  f32x4 acc[4][4];
  gemm_core(A, W, m0, n0, As, Ws, acc);

  const int t = threadIdx.x;
  const int wave = t >> 6, lane = t & 63;
  const int ln = lane & 15, qd = lane >> 4;
  const int wm = wave >> 1, wn = wave & 1;
#pragma unroll
  for (int i = 0; i < 4; i++)
#pragma unroll
    for (int j = 0; j < 4; j++)
#pragma unroll
      for (int r = 0; r < 4; r++) {
        int grow = m0 + wm * 64 + i * 16 + qd * 4 + r;
        int gcol = n0 + wn * 64 + j * 16 + ln;
        float val = (acc[i][j][r] + bias[gcol]) * mul;
        int b = grow >> 11, n = grow & 2047;
        int h = gcol >> 6, d = gcol & 63;
        O[(((size_t)b * Hdim + h) * Ndim + n) * Ddim + d] = (bf16_t)val;
      }
}

// Output projection: attn_out[8192,512] bf16 @ Wo^T + bo -> fp32 d_out
__global__ __launch_bounds__(256, 2)
void out_gemm_kernel(const bf16_t* __restrict__ ab, const bf16_t* __restrict__ wob,
                     const float* __restrict__ bo, float* __restrict__ out) {
  __shared__ bf16_t As[128 * 72];
  __shared__ bf16_t Ws[128 * 72];
  const int m0 = blockIdx.y * 128, n0 = blockIdx.x * 128;
  f32x4 acc[4][4];
  gemm_core(ab, wob, m0, n0, As, Ws, acc);

  const int t = threadIdx.x;
  const int wave = t >> 6, lane = t & 63;
  const int ln = lane & 15, qd = lane >> 4;
  const int wm = wave >> 1, wn = wave & 1;
#pragma unroll
  for (int i = 0; i < 4; i++)
#pragma unroll
    for (int j = 0; j < 4; j++)
#pragma unroll
      for (int r = 0; r < 4; r++) {
        int grow = m0 + wm * 64 + i * 16 + qd * 4 + r;
        int gcol = n0 + wn * 64 + j * 16 + ln;
        out[(size_t)grow * Cdim + gcol] = acc[i][j][r] + bo[gcol];
      }
}

// ---------------------------------------------------------------------------
// Flash-style Gumbel attention, shift-free softmax, key-split by KSPLIT.
// Per ktile: K,V prefetched into registers one iteration ahead (vmcnt wait
// hidden behind the ~3000-cycle gumbel section). Ks staged row-major in LDS;
// V staged transposed with XOR-swizzled key-blocks ((d,key) at
// d*72 + ((key>>3)^(d>>3))*8 + (key&7)). p = exp2(s*log2e) * (-rcp(log2 u));
// the global ln2 factor cancels in o/l. Partials additive across key chunks.
// LDS 27.6 KB -> 5 blocks/CU; launch_bounds(256,4) = 128-VGPR budget (no
// spills -- R7's (256,8) forced VGPR 32 and spilled ~27 MB to scratch).
// ---------------------------------------------------------------------------
__global__ __launch_bounds__(256, 4)
void attn_kernel(const bf16_t* __restrict__ qb, const bf16_t* __restrict__ kb,
                 const bf16_t* __restrict__ vb, bf16_t* __restrict__ part_o,
                 float* __restrict__ part_l) {
  __shared__ bf16_t Ks[64 * 72];
  __shared__ bf16_t Vt[64 * 72];
  __shared__ bf16_t Ps[64 * 72];

  const int t = threadIdx.x;
  const int wave = t >> 6, lane = t & 63;
  const int ln = lane & 15, qd = lane >> 4;
  const int qtile = blockIdx.x;    // 0..31
  const int bh = blockIdx.y;       // 0..31
  const int z = blockIdx.z;        // 0..KSPLIT-1
  const int qbase = qtile * 64;
  const int kt_lo = z * (Ndim / 64 / KSPLIT);
  const int kt_hi = kt_lo + (Ndim / 64 / KSPLIT);

  const bf16_t* Qg = qb + (size_t)bh * Ndim * Ddim;
  const bf16_t* Kg = kb + (size_t)bh * Ndim * Ddim;
  const bf16_t* Vg = vb + (size_t)bh * Ndim * Ddim;

  // Q A-fragments in registers: rows wave*16+ln, cols ks*32+qd*8..+8
  const bf16_t* Qrow = Qg + (size_t)(qbase + wave * 16 + ln) * Ddim;
  bf16x8 qf0 = *(const bf16x8*)&Qrow[qd * 8];
  bf16x8 qf1 = *(const bf16x8*)&Qrow[32 + qd * 8];

  // per-thread staging coordinates (2 x 16B chunks cover 64x64 tile)
  const int row0 = t >> 3,        c80 = (t & 7) * 8;
  const int row1 = (256 + t) >> 3, c81 = ((256 + t) & 7) * 8;
  const int swz0 = ((row0 >> 3) ^ (c80 >> 3)) * 8 + (row0 & 7);
  const int swz1 = ((row1 >> 3) ^ (c81 >> 3)) * 8 + (row1 & 7);

  // prefetch first tile into registers
  bf16x8 kr0 = *(const bf16x8*)&Kg[(size_t)(kt_lo * 64 + row0) * Ddim + c80];
  bf16x8 kr1 = *(const bf16x8*)&Kg[(size_t)(kt_lo * 64 + row1) * Ddim + c81];
  bf16x8 vr0 = *(const bf16x8*)&Vg[(size_t)(kt_lo * 64 + row0) * Ddim + c80];
  bf16x8 vr1 = *(const bf16x8*)&Vg[(size_t)(kt_lo * 64 + row1) * Ddim + c81];

  float l_r[4] = {0.f, 0.f, 0.f, 0.f};
  f32x4 o_acc[4];
#pragma unroll
  for (int j = 0; j < 4; j++) o_acc[j] = (f32x4){0.f, 0.f, 0.f, 0.f};

  const uint32_t flat_bh = (uint32_t)bh << 22;

  for (int kt = kt_lo; kt < kt_hi; ++kt) {
    // stage current tile from registers into LDS
    *(bf16x8*)&Ks[row0 * 72 + c80] = kr0;
    *(bf16x8*)&Ks[row1 * 72 + c81] = kr1;
#pragma unroll
    for (int jj = 0; jj < 8; jj++) Vt[(c80 + jj) * 72 + swz0] = vr0[jj];
#pragma unroll
    for (int jj = 0; jj < 8; jj++) Vt[(c81 + jj) * 72 + swz1] = vr1[jj];
    __syncthreads();

    // prefetch next tile (loads stay in flight through the compute section)
    if (kt + 1 < kt_hi) {
      kr0 = *(const bf16x8*)&Kg[(size_t)((kt + 1) * 64 + row0) * Ddim + c80];
      kr1 = *(const bf16x8*)&Kg[(size_t)((kt + 1) * 64 + row1) * Ddim + c81];
      vr0 = *(const bf16x8*)&Vg[(size_t)((kt + 1) * 64 + row0) * Ddim + c80];
      vr1 = *(const bf16x8*)&Vg[(size_t)((kt + 1) * 64 + row1) * Ddim + c81];
    }

    // S tile: wave rows 16w..16w+15, cols 64 (4 j-tiles)
    f32x4 s[4];
#pragma unroll
    for (int j = 0; j < 4; j++) s[j] = (f32x4){0.f, 0.f, 0.f, 0.f};
#pragma unroll
    for (int j = 0; j < 4; j++) {
      bf16x8 bk0 = *(const bf16x8*)&Ks[(j * 16 + ln) * 72 + qd * 8];
      bf16x8 bk1 = *(const bf16x8*)&Ks[(j * 16 + ln) * 72 + 32 + qd * 8];
      s[j] = __builtin_amdgcn_mfma_f32_16x16x32_bf16(qf0, bk0, s[j], 0, 0, 0);
      s[j] = __builtin_amdgcn_mfma_f32_16x16x32_bf16(qf1, bk1, s[j], 0, 0, 0);
    }

    // p = exp2(s*log2e) * (-rcp(log2 u)); accumulate per-lane l, stage P
#pragma unroll
    for (int r = 0; r < 4; r++) {
      int qrow = qbase + wave * 16 + qd * 4 + r;
      uint32_t fbase = flat_bh + ((uint32_t)qrow << 11) + (uint32_t)(kt * 64 + ln);
#pragma unroll
      for (int j = 0; j < 4; j++) {
        float pf = gumbel_pfac(fbase + j * 16);
        float pv = __builtin_amdgcn_exp2f(s[j][r] * LOG2E) * pf;
        l_r[r] += pv;
        Ps[(wave * 16 + qd * 4 + r) * 72 + j * 16 + ln] = (bf16_t)pv;
      }
    }
    // Ps produced and consumed by the same wave -> no barrier needed

    // O += P V  (A = P rows 16w.., B[n=d][k=key] from swizzled Vt)
#pragma unroll
    for (int ks = 0; ks < 2; ++ks) {
      bf16x8 af = *(const bf16x8*)&Ps[(wave * 16 + ln) * 72 + ks * 32 + qd * 8];
#pragma unroll
      for (int j = 0; j < 4; j++) {
        int d = j * 16 + ln;
        bf16x8 bv8 = *(const bf16x8*)&Vt[d * 72 + (((ks * 4 + qd) ^ (d >> 3)) << 3)];
        o_acc[j] = __builtin_amdgcn_mfma_f32_16x16x32_bf16(af, bv8, o_acc[j], 0, 0, 0);
      }
    }
    __syncthreads();  // protect Ks/Vt before next staging
  }

  // epilogue: bf16 o-partials + f32 l-partials
  const int pidx = ((bh << 5) | qtile) * KSPLIT + z;
  bf16_t* po = part_o + (size_t)pidx * 64 * 64;
  float* pl = part_l + (size_t)pidx * 64;

#pragma unroll
  for (int r = 0; r < 4; r++) {
    float lsum = l_r[r];
    lsum += SWZ_XOR_F(lsum, 1);
    lsum += SWZ_XOR_F(lsum, 2);
    lsum += SWZ_XOR_F(lsum, 4);
    lsum += SWZ_XOR_F(lsum, 8);
    if (ln == 0) pl[wave * 16 + qd * 4 + r] = lsum;
  }
#pragma unroll
  for (int j = 0; j < 4; j++)
#pragma unroll
    for (int r = 0; r < 4; r++) {
      int row = wave * 16 + qd * 4 + r;
      int col = j * 16 + ln;
      po[row * 64 + col] = (bf16_t)o_acc[j][r];
    }
}

// ---------------------------------------------------------------------------
// Combine: ab[b][qrow][h*64+d] = sum_z(o_z) / sum_z(l_z), bf16.
// One block per (bh,qtile); thread t: row = t>>2, 16 cols starting (t&3)*16.
// ---------------------------------------------------------------------------
__global__ __launch_bounds__(256, 8)
void attn_combine(const bf16_t* __restrict__ part_o,
                  const float* __restrict__ part_l, bf16_t* __restrict__ ab) {
  const int blk = blockIdx.x;      // bh*32 + qtile
  const int bh = blk >> 5, qtile = blk & 31;
  const int t = threadIdx.x;
  const int row = t >> 2, c0 = (t & 3) * 16;

  float l = 0.f;
#pragma unroll
  for (int zz = 0; zz < KSPLIT; zz++)
    l += part_l[(size_t)(blk * KSPLIT + zz) * 64 + row];
  const float linv = 1.0f / l;

  float acc[16];
#pragma unroll
  for (int i = 0; i < 16; i++) acc[i] = 0.f;
#pragma unroll
  for (int zz = 0; zz < KSPLIT; zz++) {
    const bf16_t* po =
        part_o + (size_t)(blk * KSPLIT + zz) * 64 * 64 + row * 64 + c0;
    bf16x8 a0 = *(const bf16x8*)&po[0];
    bf16x8 a1 = *(const bf16x8*)&po[8];
#pragma unroll
    for (int i = 0; i < 8; i++) { acc[i] += (float)a0[i]; acc[8 + i] += (float)a1[i]; }
  }

  const int b = bh >> 3, h = bh & 7;
  bf16_t* dst = ab + ((size_t)b * Ndim + qtile * 64 + row) * Cdim + h * 64 + c0;
  union { bf16_t h8[8]; uint4 u; } pk0, pk1;
#pragma unroll
  for (int i = 0; i < 8; i++) {
    pk0.h8[i] = (bf16_t)(acc[i] * linv);
    pk1.h8[i] = (bf16_t)(acc[8 + i] * linv);
  }
  *(uint4*)&dst[0] = pk0.u;
  *(uint4*)&dst[8] = pk1.u;
}

// ---------------------------------------------------------------------------
extern "C" void kernel_launch(void* const* d_in, const int* in_sizes, int n_in,
                              void* d_out, int out_size, void* d_ws, size_t ws_size,
                              hipStream_t stream) {
  const float* x  = (const float*)d_in[0];
  const float* y  = (const float*)d_in[1];
  const float* z  = (const float*)d_in[2];
  const float* Wq = (const float*)d_in[3];
  const float* bq = (const float*)d_in[4];
  const float* Wk = (const float*)d_in[5];
  const float* bk = (const float*)d_in[6];
  const float* Wv = (const float*)d_in[7];
  const float* bv = (const float*)d_in[8];
  const float* Wo = (const float*)d_in[9];
  const float* bo = (const float*)d_in[10];
  float* out = (float*)d_out;

  bf16_t* base = (bf16_t*)d_ws;
  const size_t NBIG = (size_t)Bdim * Ndim * Cdim;  // 4194304
  const size_t NW   = (size_t)Cdim * Cdim;         // 262144
  bf16_t* xb  = base;
  bf16_t* yb  = xb + NBIG;
  bf16_t* zb  = yb + NBIG;
  bf16_t* wqb = zb + NBIG;
  bf16_t* wkb = wqb + NW;
  bf16_t* wvb = wkb + NW;
  bf16_t* wob = wvb + NW;
  bf16_t* qb  = wob + NW;
  bf16_t* kb  = qb + NBIG;
  bf16_t* vb  = kb + NBIG;
  bf16_t* ab  = vb + NBIG;
  bf16_t* part_o = ab + NBIG;                       // 1024*KSPLIT*4096 bf16
  float* part_l = (float*)(part_o + (size_t)1024 * KSPLIT * 64 * 64);

  int n8b = (int)(NBIG / 8), n8w = (int)(NW / 8);
  cvt_f32_bf16<<<n8b / 256, 256, 0, stream>>>(x, xb, n8b);
  cvt_f32_bf16<<<n8b / 256, 256, 0, stream>>>(y, yb, n8b);
  cvt_f32_bf16<<<n8b / 256, 256, 0, stream>>>(z, zb, n8b);
  cvt_f32_bf16<<<n8w / 256, 256, 0, stream>>>(Wq, wqb, n8w);
  cvt_f32_bf16<<<n8w / 256, 256, 0, stream>>>(Wk, wkb, n8w);
  cvt_f32_bf16<<<n8w / 256, 256, 0, stream>>>(Wv, wvb, n8w);
  cvt_f32_bf16<<<n8w / 256, 256, 0, stream>>>(Wo, wob, n8w);

  qkv_gemm_kernel<<<dim3(Cdim / 128, (Bdim * Ndim) / 128, 3), 256, 0, stream>>>(
      xb, yb, zb, wqb, wkb, wvb, bq, bk, bv, qb, kb, vb);

  attn_kernel<<<dim3(Ndim / 64, Bdim * Hdim, KSPLIT), 256, 0, stream>>>(
      qb, kb, vb, part_o, part_l);

  attn_combine<<<dim3(1024), 256, 0, stream>>>(part_o, part_l, ab);

  out_gemm_kernel<<<dim3(Cdim / 128, (Bdim * Ndim) / 128), 256, 0, stream>>>(
      ab, wob, bo, out);
}